// Round 5
// baseline (250.697 us; speedup 1.0000x reference)
//
#include <hip/hip_runtime.h>

// PenalizedMSELoss: out = mean(w * (x - t)^2), w = 3.0 if (4.5 < x < 5.5 && t != 5) else 1.0
// x: float32[N], t: int32[N], out: float32[1]. 268 MB single-use read.
// R1: 105 us, 12 VGPR (MLP~2). R2: 115 us FAILED (32 VGPR, re-serialized).
// R3: 99 us, 28 VGPR (MLP~4). R4: asm-pin MLP=8 -> ~75 us (inferred; fills hid
//     the kernel in top-5). Harness fill runs 6.8 TB/s => chip not the limit.
// R5: MLP=16 (8 x/t pairs pinned, 64 data VGPRs), launch_bounds(256,4).

#define LABEL_I   5
#define LOWER_F   4.5f
#define UPPER_F   5.5f
#define PENALTY_F 3.0f

typedef float vf4 __attribute__((ext_vector_type(4)));
typedef int   vi4 __attribute__((ext_vector_type(4)));

__device__ __forceinline__ float term(float x, int t) {
    float d = x - (float)t;
    float w = (x > LOWER_F && x < UPPER_F && t != LABEL_I) ? PENALTY_F : 1.0f;
    return w * d * d;
}

__device__ __forceinline__ float term4(vf4 xv, vi4 tv) {
    return term(xv.x, tv.x) + term(xv.y, tv.y) + term(xv.z, tv.z) + term(xv.w, tv.w);
}

// Tile = 256 threads * 8 chunks = 2048 vf4 from each array (32 KB + 32 KB).
#define TPB 2048

__global__ __launch_bounds__(256, 4) void penal_mse_stage1(
        const vf4* __restrict__ x4,
        const vi4* __restrict__ t4,
        float* __restrict__ partials,
        int n4, int tiles, int n_tail_start, int n_total,
        const float* __restrict__ x_scalar,
        const int*  __restrict__ t_scalar) {
    float s0 = 0.0f, s1 = 0.0f, s2 = 0.0f, s3 = 0.0f;

    for (int tile = blockIdx.x; tile < tiles; tile += gridDim.x) {
        int base = tile * TPB + threadIdx.x;
        const vf4* xp = x4 + base;
        const vi4* tp = t4 + base;
        // 16 independent nontemporal 16 B loads, interleaved x/t so pair k
        // can be consumed at partial vmcnt instead of vmcnt(0).
        vf4 a0 = __builtin_nontemporal_load(xp);
        vi4 b0 = __builtin_nontemporal_load(tp);
        vf4 a1 = __builtin_nontemporal_load(xp + 256);
        vi4 b1 = __builtin_nontemporal_load(tp + 256);
        vf4 a2 = __builtin_nontemporal_load(xp + 512);
        vi4 b2 = __builtin_nontemporal_load(tp + 512);
        vf4 a3 = __builtin_nontemporal_load(xp + 768);
        vi4 b3 = __builtin_nontemporal_load(tp + 768);
        vf4 a4 = __builtin_nontemporal_load(xp + 1024);
        vi4 b4 = __builtin_nontemporal_load(tp + 1024);
        vf4 a5 = __builtin_nontemporal_load(xp + 1280);
        vi4 b5 = __builtin_nontemporal_load(tp + 1280);
        vf4 a6 = __builtin_nontemporal_load(xp + 1536);
        vi4 b6 = __builtin_nontemporal_load(tp + 1536);
        vf4 a7 = __builtin_nontemporal_load(xp + 1792);
        vi4 b7 = __builtin_nontemporal_load(tp + 1792);
        // Pin ALL 16 results live: register allocation cannot re-serialize
        // the loads (R2/R3 failure mode; R4 confirmed the pin works).
        asm volatile("" : "+v"(a0), "+v"(b0), "+v"(a1), "+v"(b1),
                          "+v"(a2), "+v"(b2), "+v"(a3), "+v"(b3),
                          "+v"(a4), "+v"(b4), "+v"(a5), "+v"(b5),
                          "+v"(a6), "+v"(b6), "+v"(a7), "+v"(b7));
        s0 += term4(a0, b0);
        s1 += term4(a1, b1);
        s2 += term4(a2, b2);
        s3 += term4(a3, b3);
        s0 += term4(a4, b4);
        s1 += term4(a5, b5);
        s2 += term4(a6, b6);
        s3 += term4(a7, b7);
    }

    float sum = (s0 + s1) + (s2 + s3);

    // Leftover vf4 groups beyond full tiles (empty for N = 2^25).
    for (int i = tiles * TPB + blockIdx.x * blockDim.x + threadIdx.x;
         i < n4; i += gridDim.x * blockDim.x)
        sum += term4(x4[i], t4[i]);

    // Scalar tail (N % 4 != 0) — empty for N = 2^25.
    for (int j = n_tail_start + blockIdx.x * blockDim.x + threadIdx.x;
         j < n_total; j += gridDim.x * blockDim.x)
        sum += term(x_scalar[j], t_scalar[j]);

    // Wave-64 shuffle reduction, then per-block partial to workspace.
    #pragma unroll
    for (int off = 32; off > 0; off >>= 1)
        sum += __shfl_down(sum, off, 64);

    __shared__ float wsum[4];
    int lane = threadIdx.x & 63;
    int wave = threadIdx.x >> 6;
    if (lane == 0) wsum[wave] = sum;
    __syncthreads();

    if (threadIdx.x == 0)
        partials[blockIdx.x] = (wsum[0] + wsum[1]) + (wsum[2] + wsum[3]);
}

__global__ __launch_bounds__(256) void penal_mse_stage2(
        const float* __restrict__ partials, int nparts,
        float* __restrict__ out, float inv_n) {
    float sum = 0.0f;
    for (int i = threadIdx.x; i < nparts; i += 256)
        sum += partials[i];

    #pragma unroll
    for (int off = 32; off > 0; off >>= 1)
        sum += __shfl_down(sum, off, 64);

    __shared__ float wsum[4];
    int lane = threadIdx.x & 63;
    int wave = threadIdx.x >> 6;
    if (lane == 0) wsum[wave] = sum;
    __syncthreads();

    if (threadIdx.x == 0)
        out[0] = ((wsum[0] + wsum[1]) + (wsum[2] + wsum[3])) * inv_n;
}

extern "C" void kernel_launch(void* const* d_in, const int* in_sizes, int n_in,
                              void* d_out, int out_size, void* d_ws, size_t ws_size,
                              hipStream_t stream) {
    const float* x = (const float*)d_in[0];
    const int*   t = (const int*)d_in[1];
    float* out = (float*)d_out;
    float* partials = (float*)d_ws;

    int n  = in_sizes[0];
    int n4 = n >> 2;              // vf4 groups
    int n_tail_start = n4 << 2;
    int tiles = n4 / TPB;         // full tiles (4096 at N = 2^25)
    float inv_n = 1.0f / (float)n;

    const int block = 256;
    const int grid = 2048;        // 2 tiles per block at N = 2^25

    penal_mse_stage1<<<grid, block, 0, stream>>>(
        (const vf4*)x, (const vi4*)t, partials,
        n4, tiles, n_tail_start, n, x, t);

    penal_mse_stage2<<<1, block, 0, stream>>>(partials, grid, out, inv_n);
}